// Round 10
// baseline (351.085 us; speedup 1.0000x reference)
//
#include <hip/hip_runtime.h>
#include <hip/hip_bf16.h>
#include <stdint.h>

typedef __bf16 bf16_t;
typedef __attribute__((ext_vector_type(8))) __bf16 bf16x8;
typedef __attribute__((ext_vector_type(4))) float f32x4;

#define DIM_IN  4096
#define DIM_OUT 4096
#define DIM_S   1024
#define DIM_S2  2048
#define NROWS   8192   // B*T = 4*2048

typedef const __attribute__((address_space(1))) void gvoid_t;
typedef __attribute__((address_space(3))) void lvoid_t;

__device__ __forceinline__ float signf(float v) {
    return (v > 0.f) ? 1.f : ((v < 0.f) ? -1.f : 0.f);
}

// ---------------- prep kernels ----------------

__global__ void cast_x_kernel(const float* __restrict__ x, bf16_t* __restrict__ xb) {
    int idx = blockIdx.x * blockDim.x + threadIdx.x;
    const float4* p = reinterpret_cast<const float4*>(x) + (size_t)idx * 2;
    float4 a = p[0], b = p[1];
    bf16x8 o;
    o[0] = (bf16_t)a.x; o[1] = (bf16_t)a.y; o[2] = (bf16_t)a.z; o[3] = (bf16_t)a.w;
    o[4] = (bf16_t)b.x; o[5] = (bf16_t)b.y; o[6] = (bf16_t)b.z; o[7] = (bf16_t)b.w;
    reinterpret_cast<bf16x8*>(xb)[idx] = o;
}

__global__ void build_vcat_kernel(const float* __restrict__ V, const float* __restrict__ v2,
                                  const float* __restrict__ V_R, const float* __restrict__ v2_R,
                                  bf16_t* __restrict__ out) {
    int idx = blockIdx.x * blockDim.x + threadIdx.x;
    int s2 = idx >> 9;
    int i0 = (idx & 511) * 8;
    const float* src; const float* sc;
    if (s2 < DIM_S) { src = V   + (size_t)s2 * DIM_IN;           sc = v2;   }
    else            { src = V_R + (size_t)(s2 - DIM_S) * DIM_IN; sc = v2_R; }
    float4 a  = *reinterpret_cast<const float4*>(src + i0);
    float4 b  = *reinterpret_cast<const float4*>(src + i0 + 4);
    float4 sa = *reinterpret_cast<const float4*>(sc + i0);
    float4 sb = *reinterpret_cast<const float4*>(sc + i0 + 4);
    bf16x8 o;
    o[0] = (bf16_t)(signf(a.x) * sa.x); o[1] = (bf16_t)(signf(a.y) * sa.y);
    o[2] = (bf16_t)(signf(a.z) * sa.z); o[3] = (bf16_t)(signf(a.w) * sa.w);
    o[4] = (bf16_t)(signf(b.x) * sb.x); o[5] = (bf16_t)(signf(b.y) * sb.y);
    o[6] = (bf16_t)(signf(b.z) * sb.z); o[7] = (bf16_t)(signf(b.w) * sb.w);
    reinterpret_cast<bf16x8*>(out)[idx] = o;
}

__global__ void build_wcat_kernel(const float* __restrict__ U, const float* __restrict__ v1,
                                  const float* __restrict__ u2, const float* __restrict__ u1,
                                  const float* __restrict__ U_R, const float* __restrict__ v1_R,
                                  const float* __restrict__ u2_R, const float* __restrict__ u1_R,
                                  bf16_t* __restrict__ out) {
    int idx = blockIdx.x * blockDim.x + threadIdx.x;
    int j  = idx >> 8;
    int s0 = (idx & 255) * 8;
    const float* srcU; const float* sv1; const float* su2; float amp;
    if (s0 < DIM_S) { srcU = U   + (size_t)j * DIM_S + s0; sv1 = v1 + s0;   su2 = u2 + s0;   amp = u1[j];   }
    else { int s = s0 - DIM_S;
           srcU = U_R + (size_t)j * DIM_S + s;  sv1 = v1_R + s; su2 = u2_R + s; amp = u1_R[j]; }
    float4 a  = *reinterpret_cast<const float4*>(srcU);
    float4 b  = *reinterpret_cast<const float4*>(srcU + 4);
    float4 va = *reinterpret_cast<const float4*>(sv1);
    float4 vb = *reinterpret_cast<const float4*>(sv1 + 4);
    float4 ua = *reinterpret_cast<const float4*>(su2);
    float4 ub = *reinterpret_cast<const float4*>(su2 + 4);
    bf16x8 o;
    o[0] = (bf16_t)(amp * va.x * ua.x * signf(a.x));
    o[1] = (bf16_t)(amp * va.y * ua.y * signf(a.y));
    o[2] = (bf16_t)(amp * va.z * ua.z * signf(a.z));
    o[3] = (bf16_t)(amp * va.w * ua.w * signf(a.w));
    o[4] = (bf16_t)(amp * vb.x * ub.x * signf(b.x));
    o[5] = (bf16_t)(amp * vb.y * ub.y * signf(b.y));
    o[6] = (bf16_t)(amp * vb.z * ub.z * signf(b.z));
    o[7] = (bf16_t)(amp * vb.w * ub.w * signf(b.w));
    reinterpret_cast<bf16x8*>(out)[idx] = o;
}

// ---------------- 128x128 2-block/CU loose-sync GEMM ----------------
// C[M][N] = A[M][K] @ B[N][K]^T. 256 thr = 4 waves (2Mx2N), per-wave 64x64
// (4m x 4n of 16x16) -> squared per-wave tile cuts LDS frag-read volume 1.5x
// vs the 256^2 (128x64/wave) structure. BK=64. LDS 64 KiB/block: A dbuf
// 2x16KB @0, B @32768 -> TWO blocks/CU, so one block's publication stall
// overlaps the other's MFMA. Staging: LDS[off] = G[off ^ (((off>>7)&7)<<4)]
// via pre-swizzled source, full 128B lines, 0 bank conflicts (r4-proven).
// Sync: ONE vmcnt(0)+barrier per K-tile at end of phase kk0 (stages issued
// at start of kk0, age ~= one MFMA cluster). Ping-pong frags; the kk1 MFMA
// is deferred past the barrier to overlap next-tile kk0 reads.

#define VMCNT0() do { asm volatile("s_waitcnt vmcnt(0)" ::: "memory"); \
                      __builtin_amdgcn_sched_barrier(0); } while (0)
#define SB0()    __builtin_amdgcn_sched_barrier(0)

template<int N, int K, bool OUT_BF16>
__global__ __launch_bounds__(256, 2) void gemm128_kernel(
        const bf16_t* __restrict__ A, const bf16_t* __restrict__ B,
        bf16_t* __restrict__ Cb, float* __restrict__ Cf,
        const float* __restrict__ bias) {
    extern __shared__ char lds[];
    constexpr int NT = K / 64;
    static_assert(NT >= 2, "K too small");
    const int tid  = threadIdx.x;
    const int wave = tid >> 6;
    const int lane = tid & 63;
    const int wr = wave >> 1;    // 0..1  (64-row M slice)
    const int wc = wave & 1;     // 0..1  (64-col N slice)

    // T1: XCD-aware bijective swizzle (nwg % 8 == 0 for both GEMMs)
    const int nwg  = gridDim.x;
    const int orig = blockIdx.x;
    const int swz  = (orig & 7) * (nwg >> 3) + (orig >> 3);
    constexpr int NTX = N / 128;
    const int n0 = (swz % NTX) * 128;
    const int m0 = (swz / NTX) * 128;

    char* ldsA = lds;            // 2 bufs x 16KB
    char* ldsB = lds + 32768;    // 2 bufs x 16KB

    // ---- staging source pointers (pre-inverse-swizzled; LDS dest linear) ----
    // per wave-instr j (j=0..3): LDS off in 16KB sub-tile = j*4096 + wave*1024
    // (+ lane*16 by HW). source row/col from lg = off ^ ((off>>7)&7)<<4.
    const char* gA[4]; const char* gB[4];
#pragma unroll
    for (int j = 0; j < 4; ++j) {
        int off = j * 4096 + wave * 1024 + lane * 16;
        int lg  = off ^ (((off >> 7) & 7) << 4);
        int row = lg >> 7;          // 0..127
        int cb  = lg & 127;         // byte within 128B row
        gA[j] = (const char*)A + (size_t)(m0 + row) * (K * 2) + cb;
        gB[j] = (const char*)B + (size_t)(n0 + row) * (K * 2) + cb;
    }

#define STAGE_A(t_) do { \
    int _lo = (((t_) & 1) << 14) + (wave << 10); \
    _Pragma("unroll") \
    for (int _j = 0; _j < 4; ++_j) \
        __builtin_amdgcn_global_load_lds((gvoid_t*)(gA[_j] + (size_t)(t_) * 128), \
                                         (lvoid_t*)(ldsA + _lo + _j * 4096), 16, 0, 0); \
} while (0)
#define STAGE_B(t_) do { \
    int _lo = (((t_) & 1) << 14) + (wave << 10); \
    _Pragma("unroll") \
    for (int _j = 0; _j < 4; ++_j) \
        __builtin_amdgcn_global_load_lds((gvoid_t*)(gB[_j] + (size_t)(t_) * 128), \
                                         (lvoid_t*)(ldsB + _lo + _j * 4096), 16, 0, 0); \
} while (0)

    // ---- swizzled read bases (kk = 32-col K-half of the 64-col tile row) ----
    const int swzmask = (lane & 7) << 4;
    int abase0, abase1, bbase0, bbase1;
    {
        int araw = (wr * 64 + (lane & 15)) * 128 + ((lane >> 4) << 4);
        abase0 = (araw ^ swzmask);
        abase1 = ((araw + 64) ^ swzmask);
        int braw = (wc * 64 + (lane & 15)) * 128 + ((lane >> 4) << 4);
        bbase0 = (braw ^ swzmask);
        bbase1 = ((braw + 64) ^ swzmask);
    }

#define RD_A4(dst, base, t_) do { \
    const int _sb = (((t_) & 1) << 14) + (base); \
    _Pragma("unroll") \
    for (int mi = 0; mi < 4; ++mi) \
        dst[mi] = *(const bf16x8*)(ldsA + _sb + mi * 2048); \
} while (0)
#define RD_B4(dst, base, t_) do { \
    const int _sb = (((t_) & 1) << 14) + (base); \
    _Pragma("unroll") \
    for (int ni = 0; ni < 4; ++ni) \
        dst[ni] = *(const bf16x8*)(ldsB + _sb + ni * 2048); \
} while (0)
#define MFMA16(AF, BF) do { \
    _Pragma("unroll") \
    for (int mi = 0; mi < 4; ++mi) \
        _Pragma("unroll") \
        for (int n = 0; n < 4; ++n) \
            acc[mi][n] = __builtin_amdgcn_mfma_f32_16x16x32_bf16( \
                AF[mi], BF[n], acc[mi][n], 0, 0, 0); \
} while (0)

    f32x4 acc[4][4];
#pragma unroll
    for (int m = 0; m < 4; ++m)
#pragma unroll
        for (int n = 0; n < 4; ++n)
            acc[m][n] = (f32x4){0.f, 0.f, 0.f, 0.f};

    bf16x8 afP[4], afQ[4], bfP[4], bfQ[4];

    // prologue: stage t=0, publish, read kk0 frags
    STAGE_A(0); STAGE_B(0);
    VMCNT0();
    __builtin_amdgcn_s_barrier();
    RD_A4(afP, abase0, 0); RD_B4(bfP, bbase0, 0);

    // Per tile: P0 (kk0): issue t+1 stages; prefetch kk1 frags; MFMA kk0;
    //           publish (vmcnt0+barrier).
    //           P1 (kk1): prefetch next tile's kk0 frags; deferred MFMA kk1.
    for (int t = 0; t < NT; ++t) {
        const bool i1 = (t + 1 < NT);
        // P0
        if (i1) { STAGE_A(t + 1); STAGE_B(t + 1); }
        RD_A4(afQ, abase1, t);
        RD_B4(bfQ, bbase1, t);
        SB0();
        MFMA16(afP, bfP);
        if (i1) { VMCNT0(); }
        __builtin_amdgcn_s_barrier();
        // P1
        if (i1) { RD_A4(afP, abase0, t + 1); RD_B4(bfP, bbase0, t + 1); }
        SB0();
        MFMA16(afQ, bfQ);
    }

#undef RD_A4
#undef RD_B4
#undef MFMA16
#undef STAGE_A
#undef STAGE_B

    // epilogue: C/D layout col=lane&15, row=(lane>>4)*4+reg (m89-verified)
    const int cr = (lane >> 4) << 2;
    const int cc = lane & 15;
#pragma unroll
    for (int m = 0; m < 4; ++m) {
        const int row = m0 + wr * 64 + m * 16 + cr;
#pragma unroll
        for (int n = 0; n < 4; ++n) {
            const int col = n0 + wc * 64 + n * 16 + cc;
            if (OUT_BF16) {
#pragma unroll
                for (int j = 0; j < 4; ++j)
                    Cb[(size_t)(row + j) * N + col] = (bf16_t)acc[m][n][j];
            } else {
                const float bv = bias[col];
#pragma unroll
                for (int j = 0; j < 4; ++j)
                    Cf[(size_t)(row + j) * N + col] = acc[m][n][j] + bv;
            }
        }
    }
}

// ---------------- launch ----------------
extern "C" void kernel_launch(void* const* d_in, const int* in_sizes, int n_in,
                              void* d_out, int out_size, void* d_ws, size_t ws_size,
                              hipStream_t stream) {
    const float* x    = (const float*)d_in[0];
    const float* V    = (const float*)d_in[1];
    const float* U    = (const float*)d_in[2];
    const float* v2   = (const float*)d_in[3];
    const float* v1   = (const float*)d_in[4];
    const float* u2   = (const float*)d_in[5];
    const float* u1   = (const float*)d_in[6];
    const float* V_R  = (const float*)d_in[7];
    const float* U_R  = (const float*)d_in[8];
    const float* v2_R = (const float*)d_in[9];
    const float* v1_R = (const float*)d_in[10];
    const float* u2_R = (const float*)d_in[11];
    const float* u1_R = (const float*)d_in[12];
    const float* bias = (const float*)d_in[13];
    float* out = (float*)d_out;

    char* ws = (char*)d_ws;
    bf16_t* Xb   = (bf16_t*)(ws);                                  // 64 MB: [8192][4096]
    bf16_t* Vcat = (bf16_t*)(ws + (size_t)64  * 1024 * 1024);      // 16 MB: [2048][4096]
    bf16_t* Wcat = (bf16_t*)(ws + (size_t)80  * 1024 * 1024);      // 16 MB: [4096][2048]
    bf16_t* Hb   = (bf16_t*)(ws + (size_t)96  * 1024 * 1024);      // 32 MB: [8192][2048]

    (void)hipFuncSetAttribute((const void*)gemm128_kernel<DIM_S2, DIM_IN, true>,
                              hipFuncAttributeMaxDynamicSharedMemorySize, 65536);
    (void)hipFuncSetAttribute((const void*)gemm128_kernel<DIM_OUT, DIM_S2, false>,
                              hipFuncAttributeMaxDynamicSharedMemorySize, 65536);

    cast_x_kernel    <<<16384, 256, 0, stream>>>(x, Xb);
    build_vcat_kernel<<<4096, 256, 0, stream>>>(V, v2, V_R, v2_R, Vcat);
    build_wcat_kernel<<<4096, 256, 0, stream>>>(U, v1, u2, u1, U_R, v1_R, u2_R, u1_R, Wcat);

    // GEMM1: H[8192][2048] = Xb @ Vcat^T   (K=4096), grid 16x64=1024
    gemm128_kernel<DIM_S2, DIM_IN, true>
        <<<(DIM_S2 / 128) * (NROWS / 128), 256, 65536, stream>>>(Xb, Vcat, Hb, nullptr, nullptr);
    // GEMM2: out[8192][4096] = Hb @ Wcat^T + bias   (K=2048), grid 32x64=2048
    gemm128_kernel<DIM_OUT, DIM_S2, false>
        <<<(DIM_OUT / 128) * (NROWS / 128), 256, 65536, stream>>>(Hb, Wcat, nullptr, out, bias);
}

// Round 11
// 340.253 us; speedup vs baseline: 1.0318x; 1.0318x over previous
//
#include <hip/hip_runtime.h>
#include <hip/hip_bf16.h>
#include <stdint.h>

typedef __bf16 bf16_t;
typedef __attribute__((ext_vector_type(8))) __bf16 bf16x8;
typedef __attribute__((ext_vector_type(4))) float f32x4;

#define DIM_IN  4096
#define DIM_OUT 4096
#define DIM_S   1024
#define DIM_S2  2048
#define NROWS   8192   // B*T = 4*2048

typedef const __attribute__((address_space(1))) void gvoid_t;
typedef __attribute__((address_space(3))) void lvoid_t;

__device__ __forceinline__ float signf(float v) {
    return (v > 0.f) ? 1.f : ((v < 0.f) ? -1.f : 0.f);
}

// ---------------- prep kernels ----------------

__global__ void cast_x_kernel(const float* __restrict__ x, bf16_t* __restrict__ xb) {
    int idx = blockIdx.x * blockDim.x + threadIdx.x;
    const float4* p = reinterpret_cast<const float4*>(x) + (size_t)idx * 2;
    float4 a = p[0], b = p[1];
    bf16x8 o;
    o[0] = (bf16_t)a.x; o[1] = (bf16_t)a.y; o[2] = (bf16_t)a.z; o[3] = (bf16_t)a.w;
    o[4] = (bf16_t)b.x; o[5] = (bf16_t)b.y; o[6] = (bf16_t)b.z; o[7] = (bf16_t)b.w;
    reinterpret_cast<bf16x8*>(xb)[idx] = o;
}

__global__ void build_vcat_kernel(const float* __restrict__ V, const float* __restrict__ v2,
                                  const float* __restrict__ V_R, const float* __restrict__ v2_R,
                                  bf16_t* __restrict__ out) {
    int idx = blockIdx.x * blockDim.x + threadIdx.x;
    int s2 = idx >> 9;
    int i0 = (idx & 511) * 8;
    const float* src; const float* sc;
    if (s2 < DIM_S) { src = V   + (size_t)s2 * DIM_IN;           sc = v2;   }
    else            { src = V_R + (size_t)(s2 - DIM_S) * DIM_IN; sc = v2_R; }
    float4 a  = *reinterpret_cast<const float4*>(src + i0);
    float4 b  = *reinterpret_cast<const float4*>(src + i0 + 4);
    float4 sa = *reinterpret_cast<const float4*>(sc + i0);
    float4 sb = *reinterpret_cast<const float4*>(sc + i0 + 4);
    bf16x8 o;
    o[0] = (bf16_t)(signf(a.x) * sa.x); o[1] = (bf16_t)(signf(a.y) * sa.y);
    o[2] = (bf16_t)(signf(a.z) * sa.z); o[3] = (bf16_t)(signf(a.w) * sa.w);
    o[4] = (bf16_t)(signf(b.x) * sb.x); o[5] = (bf16_t)(signf(b.y) * sb.y);
    o[6] = (bf16_t)(signf(b.z) * sb.z); o[7] = (bf16_t)(signf(b.w) * sb.w);
    reinterpret_cast<bf16x8*>(out)[idx] = o;
}

__global__ void build_wcat_kernel(const float* __restrict__ U, const float* __restrict__ v1,
                                  const float* __restrict__ u2, const float* __restrict__ u1,
                                  const float* __restrict__ U_R, const float* __restrict__ v1_R,
                                  const float* __restrict__ u2_R, const float* __restrict__ u1_R,
                                  bf16_t* __restrict__ out) {
    int idx = blockIdx.x * blockDim.x + threadIdx.x;
    int j  = idx >> 8;
    int s0 = (idx & 255) * 8;
    const float* srcU; const float* sv1; const float* su2; float amp;
    if (s0 < DIM_S) { srcU = U   + (size_t)j * DIM_S + s0; sv1 = v1 + s0;   su2 = u2 + s0;   amp = u1[j];   }
    else { int s = s0 - DIM_S;
           srcU = U_R + (size_t)j * DIM_S + s;  sv1 = v1_R + s; su2 = u2_R + s; amp = u1_R[j]; }
    float4 a  = *reinterpret_cast<const float4*>(srcU);
    float4 b  = *reinterpret_cast<const float4*>(srcU + 4);
    float4 va = *reinterpret_cast<const float4*>(sv1);
    float4 vb = *reinterpret_cast<const float4*>(sv1 + 4);
    float4 ua = *reinterpret_cast<const float4*>(su2);
    float4 ub = *reinterpret_cast<const float4*>(su2 + 4);
    bf16x8 o;
    o[0] = (bf16_t)(amp * va.x * ua.x * signf(a.x));
    o[1] = (bf16_t)(amp * va.y * ua.y * signf(a.y));
    o[2] = (bf16_t)(amp * va.z * ua.z * signf(a.z));
    o[3] = (bf16_t)(amp * va.w * ua.w * signf(a.w));
    o[4] = (bf16_t)(amp * vb.x * ub.x * signf(b.x));
    o[5] = (bf16_t)(amp * vb.y * ub.y * signf(b.y));
    o[6] = (bf16_t)(amp * vb.z * ub.z * signf(b.z));
    o[7] = (bf16_t)(amp * vb.w * ub.w * signf(b.w));
    reinterpret_cast<bf16x8*>(out)[idx] = o;
}

// ---------------- 128x128 2-block/CU loose-sync GEMM (r11: aged staging) ----------------
// C[M][N] = A[M][K] @ B[N][K]^T. 256 thr = 4 waves (2Mx2N), per-wave 64x64
// (4m x 4n of 16x16). BK=64. LDS 64 KiB/block (A dbuf 2x16KB @0, B @32768)
// -> 2 blocks/CU. Staging: LDS[off] = G[off ^ (((off>>7)&7)<<4)] via
// pre-swizzled source, full 128B lines, 0 bank conflicts.
// r11 fix vs r10: STAGE(t+2) issues at P1 of tile t (buf(t&1) is dead there:
// its last ds_reads were at P0(t), ordered by the P0-end barrier), so each
// stage ages a FULL K-tile (P1+P0 > HBM latency) before its vmcnt(0) drain.
// r10 issued at P0(t) and drained at P0-end(t) -> exposed ~900cy HBM latency
// per tile (MfmaUtil 34%).

#define VMCNT0() do { asm volatile("s_waitcnt vmcnt(0)" ::: "memory"); \
                      __builtin_amdgcn_sched_barrier(0); } while (0)
#define SB0()    __builtin_amdgcn_sched_barrier(0)

template<int N, int K, bool OUT_BF16>
__global__ __launch_bounds__(256, 2) void gemm128_kernel(
        const bf16_t* __restrict__ A, const bf16_t* __restrict__ B,
        bf16_t* __restrict__ Cb, float* __restrict__ Cf,
        const float* __restrict__ bias) {
    extern __shared__ char lds[];
    constexpr int NT = K / 64;
    static_assert(NT >= 2, "K too small");
    const int tid  = threadIdx.x;
    const int wave = tid >> 6;
    const int lane = tid & 63;
    const int wr = wave >> 1;    // 0..1  (64-row M slice)
    const int wc = wave & 1;     // 0..1  (64-col N slice)

    // T1: XCD-aware bijective swizzle (nwg % 8 == 0 for both GEMMs)
    const int nwg  = gridDim.x;
    const int orig = blockIdx.x;
    const int swz  = (orig & 7) * (nwg >> 3) + (orig >> 3);
    constexpr int NTX = N / 128;
    const int n0 = (swz % NTX) * 128;
    const int m0 = (swz / NTX) * 128;

    char* ldsA = lds;            // 2 bufs x 16KB
    char* ldsB = lds + 32768;    // 2 bufs x 16KB

    // ---- staging source pointers (pre-inverse-swizzled; LDS dest linear) ----
    const char* gA[4]; const char* gB[4];
#pragma unroll
    for (int j = 0; j < 4; ++j) {
        int off = j * 4096 + wave * 1024 + lane * 16;
        int lg  = off ^ (((off >> 7) & 7) << 4);
        int row = lg >> 7;          // 0..127
        int cb  = lg & 127;         // byte within 128B row
        gA[j] = (const char*)A + (size_t)(m0 + row) * (K * 2) + cb;
        gB[j] = (const char*)B + (size_t)(n0 + row) * (K * 2) + cb;
    }

#define STAGE_A(t_) do { \
    int _lo = (((t_) & 1) << 14) + (wave << 10); \
    _Pragma("unroll") \
    for (int _j = 0; _j < 4; ++_j) \
        __builtin_amdgcn_global_load_lds((gvoid_t*)(gA[_j] + (size_t)(t_) * 128), \
                                         (lvoid_t*)(ldsA + _lo + _j * 4096), 16, 0, 0); \
} while (0)
#define STAGE_B(t_) do { \
    int _lo = (((t_) & 1) << 14) + (wave << 10); \
    _Pragma("unroll") \
    for (int _j = 0; _j < 4; ++_j) \
        __builtin_amdgcn_global_load_lds((gvoid_t*)(gB[_j] + (size_t)(t_) * 128), \
                                         (lvoid_t*)(ldsB + _lo + _j * 4096), 16, 0, 0); \
} while (0)

    // ---- swizzled read bases (kk = 32-col K-half of the 64-col tile row) ----
    const int swzmask = (lane & 7) << 4;
    int abase0, abase1, bbase0, bbase1;
    {
        int araw = (wr * 64 + (lane & 15)) * 128 + ((lane >> 4) << 4);
        abase0 = (araw ^ swzmask);
        abase1 = ((araw + 64) ^ swzmask);
        int braw = (wc * 64 + (lane & 15)) * 128 + ((lane >> 4) << 4);
        bbase0 = (braw ^ swzmask);
        bbase1 = ((braw + 64) ^ swzmask);
    }

#define RD_A4(dst, base, t_) do { \
    const int _sb = (((t_) & 1) << 14) + (base); \
    _Pragma("unroll") \
    for (int mi = 0; mi < 4; ++mi) \
        dst[mi] = *(const bf16x8*)(ldsA + _sb + mi * 2048); \
} while (0)
#define RD_B4(dst, base, t_) do { \
    const int _sb = (((t_) & 1) << 14) + (base); \
    _Pragma("unroll") \
    for (int ni = 0; ni < 4; ++ni) \
        dst[ni] = *(const bf16x8*)(ldsB + _sb + ni * 2048); \
} while (0)
#define MFMA16(AF, BF) do { \
    _Pragma("unroll") \
    for (int mi = 0; mi < 4; ++mi) \
        _Pragma("unroll") \
        for (int n = 0; n < 4; ++n) \
            acc[mi][n] = __builtin_amdgcn_mfma_f32_16x16x32_bf16( \
                AF[mi], BF[n], acc[mi][n], 0, 0, 0); \
} while (0)

    f32x4 acc[4][4];
#pragma unroll
    for (int m = 0; m < 4; ++m)
#pragma unroll
        for (int n = 0; n < 4; ++n)
            acc[m][n] = (f32x4){0.f, 0.f, 0.f, 0.f};

    bf16x8 afP[4], afQ[4], bfP[4], bfQ[4];

    // prologue: stage t=0, publish, read kk0 frags; then issue t=1 stages
    STAGE_A(0); STAGE_B(0);
    VMCNT0();
    __builtin_amdgcn_s_barrier();
    RD_A4(afP, abase0, 0); RD_B4(bfP, bbase0, 0);
    STAGE_A(1); STAGE_B(1);     // ages through P0(0) before its drain

    // Per tile: P0 (kk0): prefetch kk1 frags; MFMA kk0; vmcnt(0)+barrier
    //                     (publishes t+1, staged one phase earlier).
    //           P1 (kk1): issue STAGE(t+2) into the now-dead buf(t&1);
    //                     prefetch next tile's kk0 frags; deferred MFMA kk1.
    for (int t = 0; t < NT; ++t) {
        const bool i1 = (t + 1 < NT);
        // P0
        RD_A4(afQ, abase1, t);
        RD_B4(bfQ, bbase1, t);
        SB0();
        MFMA16(afP, bfP);
        if (i1) { VMCNT0(); }
        __builtin_amdgcn_s_barrier();
        // P1
        if (t + 2 < NT) { STAGE_A(t + 2); STAGE_B(t + 2); }
        if (i1) { RD_A4(afP, abase0, t + 1); RD_B4(bfP, bbase0, t + 1); }
        SB0();
        MFMA16(afQ, bfQ);
    }

#undef RD_A4
#undef RD_B4
#undef MFMA16
#undef STAGE_A
#undef STAGE_B

    // epilogue: C/D layout col=lane&15, row=(lane>>4)*4+reg (m89-verified)
    const int cr = (lane >> 4) << 2;
    const int cc = lane & 15;
#pragma unroll
    for (int m = 0; m < 4; ++m) {
        const int row = m0 + wr * 64 + m * 16 + cr;
#pragma unroll
        for (int n = 0; n < 4; ++n) {
            const int col = n0 + wc * 64 + n * 16 + cc;
            if (OUT_BF16) {
#pragma unroll
                for (int j = 0; j < 4; ++j)
                    Cb[(size_t)(row + j) * N + col] = (bf16_t)acc[m][n][j];
            } else {
                const float bv = bias[col];
#pragma unroll
                for (int j = 0; j < 4; ++j)
                    Cf[(size_t)(row + j) * N + col] = acc[m][n][j] + bv;
            }
        }
    }
}

// ---------------- launch ----------------
extern "C" void kernel_launch(void* const* d_in, const int* in_sizes, int n_in,
                              void* d_out, int out_size, void* d_ws, size_t ws_size,
                              hipStream_t stream) {
    const float* x    = (const float*)d_in[0];
    const float* V    = (const float*)d_in[1];
    const float* U    = (const float*)d_in[2];
    const float* v2   = (const float*)d_in[3];
    const float* v1   = (const float*)d_in[4];
    const float* u2   = (const float*)d_in[5];
    const float* u1   = (const float*)d_in[6];
    const float* V_R  = (const float*)d_in[7];
    const float* U_R  = (const float*)d_in[8];
    const float* v2_R = (const float*)d_in[9];
    const float* v1_R = (const float*)d_in[10];
    const float* u2_R = (const float*)d_in[11];
    const float* u1_R = (const float*)d_in[12];
    const float* bias = (const float*)d_in[13];
    float* out = (float*)d_out;

    char* ws = (char*)d_ws;
    bf16_t* Xb   = (bf16_t*)(ws);                                  // 64 MB: [8192][4096]
    bf16_t* Vcat = (bf16_t*)(ws + (size_t)64  * 1024 * 1024);      // 16 MB: [2048][4096]
    bf16_t* Wcat = (bf16_t*)(ws + (size_t)80  * 1024 * 1024);      // 16 MB: [4096][2048]
    bf16_t* Hb   = (bf16_t*)(ws + (size_t)96  * 1024 * 1024);      // 32 MB: [8192][2048]

    (void)hipFuncSetAttribute((const void*)gemm128_kernel<DIM_S2, DIM_IN, true>,
                              hipFuncAttributeMaxDynamicSharedMemorySize, 65536);
    (void)hipFuncSetAttribute((const void*)gemm128_kernel<DIM_OUT, DIM_S2, false>,
                              hipFuncAttributeMaxDynamicSharedMemorySize, 65536);

    cast_x_kernel    <<<16384, 256, 0, stream>>>(x, Xb);
    build_vcat_kernel<<<4096, 256, 0, stream>>>(V, v2, V_R, v2_R, Vcat);
    build_wcat_kernel<<<4096, 256, 0, stream>>>(U, v1, u2, u1, U_R, v1_R, u2_R, u1_R, Wcat);

    // GEMM1: H[8192][2048] = Xb @ Vcat^T   (K=4096), grid 16x64=1024
    gemm128_kernel<DIM_S2, DIM_IN, true>
        <<<(DIM_S2 / 128) * (NROWS / 128), 256, 65536, stream>>>(Xb, Vcat, Hb, nullptr, nullptr);
    // GEMM2: out[8192][4096] = Hb @ Wcat^T + bias   (K=2048), grid 32x64=2048
    gemm128_kernel<DIM_OUT, DIM_S2, false>
        <<<(DIM_OUT / 128) * (NROWS / 128), 256, 65536, stream>>>(Hb, Wcat, nullptr, out, bias);
}

// Round 12
// 283.286 us; speedup vs baseline: 1.2393x; 1.2011x over previous
//
#include <hip/hip_runtime.h>
#include <hip/hip_bf16.h>
#include <stdint.h>

typedef __bf16 bf16_t;
typedef __attribute__((ext_vector_type(8))) __bf16 bf16x8;
typedef __attribute__((ext_vector_type(4))) float f32x4;

#define DIM_IN  4096
#define DIM_OUT 4096
#define DIM_S   1024
#define DIM_S2  2048
#define NROWS   8192   // B*T = 4*2048

typedef const __attribute__((address_space(1))) void gvoid_t;
typedef __attribute__((address_space(3))) void lvoid_t;

__device__ __forceinline__ float signf(float v) {
    return (v > 0.f) ? 1.f : ((v < 0.f) ? -1.f : 0.f);
}

// ---------------- prep kernels ----------------

__global__ void cast_x_kernel(const float* __restrict__ x, bf16_t* __restrict__ xb) {
    int idx = blockIdx.x * blockDim.x + threadIdx.x;
    const float4* p = reinterpret_cast<const float4*>(x) + (size_t)idx * 2;
    float4 a = p[0], b = p[1];
    bf16x8 o;
    o[0] = (bf16_t)a.x; o[1] = (bf16_t)a.y; o[2] = (bf16_t)a.z; o[3] = (bf16_t)a.w;
    o[4] = (bf16_t)b.x; o[5] = (bf16_t)b.y; o[6] = (bf16_t)b.z; o[7] = (bf16_t)b.w;
    reinterpret_cast<bf16x8*>(xb)[idx] = o;
}

__global__ void build_vcat_kernel(const float* __restrict__ V, const float* __restrict__ v2,
                                  const float* __restrict__ V_R, const float* __restrict__ v2_R,
                                  bf16_t* __restrict__ out) {
    int idx = blockIdx.x * blockDim.x + threadIdx.x;
    int s2 = idx >> 9;
    int i0 = (idx & 511) * 8;
    const float* src; const float* sc;
    if (s2 < DIM_S) { src = V   + (size_t)s2 * DIM_IN;           sc = v2;   }
    else            { src = V_R + (size_t)(s2 - DIM_S) * DIM_IN; sc = v2_R; }
    float4 a  = *reinterpret_cast<const float4*>(src + i0);
    float4 b  = *reinterpret_cast<const float4*>(src + i0 + 4);
    float4 sa = *reinterpret_cast<const float4*>(sc + i0);
    float4 sb = *reinterpret_cast<const float4*>(sc + i0 + 4);
    bf16x8 o;
    o[0] = (bf16_t)(signf(a.x) * sa.x); o[1] = (bf16_t)(signf(a.y) * sa.y);
    o[2] = (bf16_t)(signf(a.z) * sa.z); o[3] = (bf16_t)(signf(a.w) * sa.w);
    o[4] = (bf16_t)(signf(b.x) * sb.x); o[5] = (bf16_t)(signf(b.y) * sb.y);
    o[6] = (bf16_t)(signf(b.z) * sb.z); o[7] = (bf16_t)(signf(b.w) * sb.w);
    reinterpret_cast<bf16x8*>(out)[idx] = o;
}

__global__ void build_wcat_kernel(const float* __restrict__ U, const float* __restrict__ v1,
                                  const float* __restrict__ u2, const float* __restrict__ u1,
                                  const float* __restrict__ U_R, const float* __restrict__ v1_R,
                                  const float* __restrict__ u2_R, const float* __restrict__ u1_R,
                                  bf16_t* __restrict__ out) {
    int idx = blockIdx.x * blockDim.x + threadIdx.x;
    int j  = idx >> 8;
    int s0 = (idx & 255) * 8;
    const float* srcU; const float* sv1; const float* su2; float amp;
    if (s0 < DIM_S) { srcU = U   + (size_t)j * DIM_S + s0; sv1 = v1 + s0;   su2 = u2 + s0;   amp = u1[j];   }
    else { int s = s0 - DIM_S;
           srcU = U_R + (size_t)j * DIM_S + s;  sv1 = v1_R + s; su2 = u2_R + s; amp = u1_R[j]; }
    float4 a  = *reinterpret_cast<const float4*>(srcU);
    float4 b  = *reinterpret_cast<const float4*>(srcU + 4);
    float4 va = *reinterpret_cast<const float4*>(sv1);
    float4 vb = *reinterpret_cast<const float4*>(sv1 + 4);
    float4 ua = *reinterpret_cast<const float4*>(su2);
    float4 ub = *reinterpret_cast<const float4*>(su2 + 4);
    bf16x8 o;
    o[0] = (bf16_t)(amp * va.x * ua.x * signf(a.x));
    o[1] = (bf16_t)(amp * va.y * ua.y * signf(a.y));
    o[2] = (bf16_t)(amp * va.z * ua.z * signf(a.z));
    o[3] = (bf16_t)(amp * va.w * ua.w * signf(a.w));
    o[4] = (bf16_t)(amp * vb.x * ub.x * signf(b.x));
    o[5] = (bf16_t)(amp * vb.y * ub.y * signf(b.y));
    o[6] = (bf16_t)(amp * vb.z * ub.z * signf(b.z));
    o[7] = (bf16_t)(amp * vb.w * ub.w * signf(b.w));
    reinterpret_cast<bf16x8*>(out)[idx] = o;
}

// ---------------- 256x256 loose-sync GEMM + phase-pipelined frags ----------------
// Session-best structure (r9, 283.6 us total). C[M][N] = A[M][K] @ B[N][K]^T.
// 512 thr = 8 waves (2Mx4N), per-wave 128x64 (8m x 4n of 16x16), BK=64.
// LDS 128 KiB, sub-tile [128 rows][64 cols] per mh/nh, dbuf.
// Staging: LDS[off] = G[off ^ (((off>>7)&7)<<4)] (pre-swizzled source, full
// 128B lines, 0 bank conflicts). Sync: ONE vmcnt(0)+barrier per K-tile.
// Frag ds_reads one phase ahead into ping-pong regs; last MFMA cluster
// deferred past the tile-end barrier.

#define VMCNT0() do { asm volatile("s_waitcnt vmcnt(0)" ::: "memory"); \
                      __builtin_amdgcn_sched_barrier(0); } while (0)
#define SB0()    __builtin_amdgcn_sched_barrier(0)

template<int N, int K, bool OUT_BF16>
__global__ __launch_bounds__(512, 2) void gemm256_kernel(
        const bf16_t* __restrict__ A, const bf16_t* __restrict__ B,
        bf16_t* __restrict__ Cb, float* __restrict__ Cf,
        const float* __restrict__ bias) {
    extern __shared__ char lds[];
    constexpr int NT = K / 64;
    static_assert(NT >= 2, "K too small");
    const int tid  = threadIdx.x;
    const int wave = tid >> 6;
    const int lane = tid & 63;
    const int wr = wave >> 2;    // 0..1  (M-half)
    const int wc = wave & 3;     // 0..3  (64-col N slice)

    // T1: XCD-aware bijective swizzle (nwg % 8 == 0 for both GEMMs)
    const int nwg  = gridDim.x;
    const int orig = blockIdx.x;
    const int swz  = (orig & 7) * (nwg >> 3) + (orig >> 3);
    constexpr int NTX = N / 256;
    const int n0 = (swz % NTX) * 256;
    const int m0 = (swz / NTX) * 256;

    char* ldsA = lds;
    char* ldsB = lds + 65536;

    // ---- staging source pointers (pre-inverse-swizzled; LDS dest linear) ----
    const char* gA[2]; const char* gB[2];
#pragma unroll
    for (int j = 0; j < 2; ++j) {
        int off = j * 8192 + wave * 1024 + lane * 16;
        int lg  = off ^ (((off >> 7) & 7) << 4);
        int row = lg >> 7;          // 0..127
        int cb  = lg & 127;         // byte within 128B row
        gA[j] = (const char*)A + (size_t)(m0 + row) * (K * 2) + cb;
        gB[j] = (const char*)B + (size_t)(n0 + row) * (K * 2) + cb;
    }

#define STAGE_A(t_, mh) do { \
    int _lo = (((t_) & 1) << 15) + ((mh) << 14) + (wave << 10); \
    size_t _ga = (size_t)(mh) * (128 * (size_t)K * 2) + (size_t)(t_) * 128; \
    __builtin_amdgcn_global_load_lds((gvoid_t*)(gA[0] + _ga), (lvoid_t*)(ldsA + _lo), 16, 0, 0); \
    __builtin_amdgcn_global_load_lds((gvoid_t*)(gA[1] + _ga), (lvoid_t*)(ldsA + _lo + 8192), 16, 0, 0); \
} while (0)
#define STAGE_B(t_, nh) do { \
    int _lo = (((t_) & 1) << 15) + ((nh) << 14) + (wave << 10); \
    size_t _ga = (size_t)(nh) * (128 * (size_t)K * 2) + (size_t)(t_) * 128; \
    __builtin_amdgcn_global_load_lds((gvoid_t*)(gB[0] + _ga), (lvoid_t*)(ldsB + _lo), 16, 0, 0); \
    __builtin_amdgcn_global_load_lds((gvoid_t*)(gB[1] + _ga), (lvoid_t*)(ldsB + _lo + 8192), 16, 0, 0); \
} while (0)

    // ---- swizzled read bases (kk = 32-col K-half) ----
    const int swzmask = (lane & 7) << 4;
    int abase0, abase1, bbase0, bbase1;
    {
        int araw = (lane & 15) * 128 + ((lane >> 4) << 4);
        abase0 = (araw ^ swzmask) + (wr << 14);
        abase1 = ((araw + 64) ^ swzmask) + (wr << 14);
        int braw = ((wc & 1) * 64 + (lane & 15)) * 128 + ((lane >> 4) << 4);
        bbase0 = (braw ^ swzmask) + ((wc >> 1) << 14);
        bbase1 = ((braw + 64) ^ swzmask) + ((wc >> 1) << 14);
    }

#define RD_A4(dst, base, mg, t_) do { \
    const int _sb = (((t_) & 1) << 15) + (base); \
    _Pragma("unroll") \
    for (int mi = 0; mi < 4; ++mi) \
        dst[mi] = *(const bf16x8*)(ldsA + _sb + ((mg) * 4 + mi) * 2048); \
} while (0)
#define RD_B4(dst, base, t_) do { \
    const int _sb = (((t_) & 1) << 15) + (base); \
    _Pragma("unroll") \
    for (int ni = 0; ni < 4; ++ni) \
        dst[ni] = *(const bf16x8*)(ldsB + _sb + ni * 2048); \
} while (0)
#define RD_B2(dst, base, h_, t_) do { \
    const int _sb = (((t_) & 1) << 15) + (base); \
    _Pragma("unroll") \
    for (int ni = 0; ni < 2; ++ni) \
        dst[(h_) * 2 + ni] = *(const bf16x8*)(ldsB + _sb + ((h_) * 2 + ni) * 2048); \
} while (0)
#define MFMA16(mg, AF, BF) do { \
    _Pragma("unroll") \
    for (int mi = 0; mi < 4; ++mi) \
        _Pragma("unroll") \
        for (int n = 0; n < 4; ++n) \
            acc[(mg) * 4 + mi][n] = __builtin_amdgcn_mfma_f32_16x16x32_bf16( \
                AF[mi], BF[n], acc[(mg) * 4 + mi][n], 0, 0, 0); \
} while (0)

    f32x4 acc[8][4];
#pragma unroll
    for (int m = 0; m < 8; ++m)
#pragma unroll
        for (int n = 0; n < 4; ++n)
            acc[m][n] = (f32x4){0.f, 0.f, 0.f, 0.f};

    bf16x8 afP[4], afQ[4], bf0[4], bf1[4];

    // prologue: stage all 4 sub-tiles of t=0, publish, read P0's frags
    STAGE_A(0, 0); STAGE_A(0, 1);
    STAGE_B(0, 0); STAGE_B(0, 1);
    VMCNT0();
    __builtin_amdgcn_s_barrier();
    RD_A4(afP, abase0, 0, 0); RD_B4(bf0, bbase0, 0);

    // Phases per tile: P0=(mg0,kk0) P1=(mg1,kk0) P2=(mg0,kk1) P3=(mg1,kk1).
    // Each phase issues the NEXT phase's frag reads before its MFMA cluster.
    for (int t = 0; t < NT; ++t) {
        const bool i1 = (t + 1 < NT);
        // P0: prefetch P1 A-frags + first half of kk1 B-frags; issue A stages
        if (i1) { STAGE_A(t + 1, 0); STAGE_A(t + 1, 1); }
        RD_A4(afQ, abase0, 1, t);
        RD_B2(bf1, bbase1, 0, t);
        SB0();
        MFMA16(0, afP, bf0);
        // P1: prefetch P2 A-frags + second half of kk1 B-frags; issue B stages
        if (i1) { STAGE_B(t + 1, 0); STAGE_B(t + 1, 1); }
        RD_A4(afP, abase1, 0, t);
        RD_B2(bf1, bbase1, 1, t);
        SB0();
        MFMA16(1, afQ, bf0);
        // P2: prefetch P3 A-frags
        RD_A4(afQ, abase1, 1, t);
        SB0();
        MFMA16(0, afP, bf1);
        // P3: publish next tile; prefetch its P0 frags; deferred MFMA
        VMCNT0();
        __builtin_amdgcn_s_barrier();
        if (i1) { RD_A4(afP, abase0, 0, t + 1); RD_B4(bf0, bbase0, t + 1); }
        SB0();
        MFMA16(1, afQ, bf1);
    }

#undef RD_A4
#undef RD_B4
#undef RD_B2
#undef MFMA16
#undef STAGE_A
#undef STAGE_B

    // epilogue: C/D layout col=lane&15, row=(lane>>4)*4+reg (m89-verified)
    const int cr = (lane >> 4) << 2;
    const int cc = lane & 15;
#pragma unroll
    for (int m = 0; m < 8; ++m) {
        const int row = m0 + wr * 128 + m * 16 + cr;
#pragma unroll
        for (int n = 0; n < 4; ++n) {
            const int col = n0 + wc * 64 + n * 16 + cc;
            if (OUT_BF16) {
#pragma unroll
                for (int j = 0; j < 4; ++j)
                    Cb[(size_t)(row + j) * N + col] = (bf16_t)acc[m][n][j];
            } else {
                const float bv = bias[col];
#pragma unroll
                for (int j = 0; j < 4; ++j)
                    Cf[(size_t)(row + j) * N + col] = acc[m][n][j] + bv;
            }
        }
    }
}

// ---------------- launch ----------------
extern "C" void kernel_launch(void* const* d_in, const int* in_sizes, int n_in,
                              void* d_out, int out_size, void* d_ws, size_t ws_size,
                              hipStream_t stream) {
    const float* x    = (const float*)d_in[0];
    const float* V    = (const float*)d_in[1];
    const float* U    = (const float*)d_in[2];
    const float* v2   = (const float*)d_in[3];
    const float* v1   = (const float*)d_in[4];
    const float* u2   = (const float*)d_in[5];
    const float* u1   = (const float*)d_in[6];
    const float* V_R  = (const float*)d_in[7];
    const float* U_R  = (const float*)d_in[8];
    const float* v2_R = (const float*)d_in[9];
    const float* v1_R = (const float*)d_in[10];
    const float* u2_R = (const float*)d_in[11];
    const float* u1_R = (const float*)d_in[12];
    const float* bias = (const float*)d_in[13];
    float* out = (float*)d_out;

    char* ws = (char*)d_ws;
    bf16_t* Xb   = (bf16_t*)(ws);                                  // 64 MB: [8192][4096]
    bf16_t* Vcat = (bf16_t*)(ws + (size_t)64  * 1024 * 1024);      // 16 MB: [2048][4096]
    bf16_t* Wcat = (bf16_t*)(ws + (size_t)80  * 1024 * 1024);      // 16 MB: [4096][2048]
    bf16_t* Hb   = (bf16_t*)(ws + (size_t)96  * 1024 * 1024);      // 32 MB: [8192][2048]

    (void)hipFuncSetAttribute((const void*)gemm256_kernel<DIM_S2, DIM_IN, true>,
                              hipFuncAttributeMaxDynamicSharedMemorySize, 131072);
    (void)hipFuncSetAttribute((const void*)gemm256_kernel<DIM_OUT, DIM_S2, false>,
                              hipFuncAttributeMaxDynamicSharedMemorySize, 131072);

    cast_x_kernel    <<<16384, 256, 0, stream>>>(x, Xb);
    build_vcat_kernel<<<4096, 256, 0, stream>>>(V, v2, V_R, v2_R, Vcat);
    build_wcat_kernel<<<4096, 256, 0, stream>>>(U, v1, u2, u1, U_R, v1_R, u2_R, u1_R, Wcat);

    // GEMM1: H[8192][2048] = Xb @ Vcat^T   (K=4096), grid 8x32=256
    gemm256_kernel<DIM_S2, DIM_IN, true>
        <<<(DIM_S2 / 256) * (NROWS / 256), 512, 131072, stream>>>(Xb, Vcat, Hb, nullptr, nullptr);
    // GEMM2: out[8192][4096] = Hb @ Wcat^T + bias   (K=2048), grid 16x32=512
    gemm256_kernel<DIM_OUT, DIM_S2, false>
        <<<(DIM_OUT / 256) * (NROWS / 256), 512, 131072, stream>>>(Hb, Wcat, nullptr, out, bias);
}